// Round 3
// baseline (190.500 us; speedup 1.0000x reference)
//
#include <hip/hip_runtime.h>

// Leave-one-out mean along dim 1.
// x: [ROWS, NCOLS] f32, out[b,i] = (row_sum[b] - x[b,i]) / (NCOLS - 1).
// Round 3: 512-thread blocks (8x float4 per thread) -> 4 blocks/CU instead
// of 2, finer cross-block overlap of load/store phases, half the waves per
// barrier. Nontemporal loads+stores kept (touch-once streams, bypass L2).

#define NCOLS 16384
#define BLOCK 512
#define PER_THREAD_V4 8   // NCOLS / 4 / BLOCK

using f32x4 = __attribute__((ext_vector_type(4))) float;

__global__ __launch_bounds__(BLOCK) void loo_mean_kernel(
    const float* __restrict__ x, float* __restrict__ out) {
    const int row = blockIdx.x;
    const f32x4* __restrict__ xr =
        reinterpret_cast<const f32x4*>(x + (size_t)row * NCOLS);
    f32x4* __restrict__ outr =
        reinterpret_cast<f32x4*>(out + (size_t)row * NCOLS);
    const int tid = threadIdx.x;

    f32x4 v[PER_THREAD_V4];
    float s = 0.0f;
#pragma unroll
    for (int i = 0; i < PER_THREAD_V4; ++i) {
        v[i] = __builtin_nontemporal_load(&xr[tid + i * BLOCK]);
        s += (v[i].x + v[i].y) + (v[i].z + v[i].w);
    }

    // Wave-64 butterfly reduce
#pragma unroll
    for (int off = 32; off >= 1; off >>= 1)
        s += __shfl_down(s, off, 64);

    __shared__ float partial[BLOCK / 64];
    __shared__ float total_sh;
    const int wave = tid >> 6;
    const int lane = tid & 63;
    if (lane == 0) partial[wave] = s;
    __syncthreads();
    if (tid == 0) {
        float t = 0.0f;
#pragma unroll
        for (int w = 0; w < BLOCK / 64; ++w) t += partial[w];
        total_sh = t;
    }
    __syncthreads();

    const float total = total_sh;
    const float inv = 1.0f / (float)(NCOLS - 1);
#pragma unroll
    for (int i = 0; i < PER_THREAD_V4; ++i) {
        f32x4 o;
        o.x = (total - v[i].x) * inv;
        o.y = (total - v[i].y) * inv;
        o.z = (total - v[i].z) * inv;
        o.w = (total - v[i].w) * inv;
        __builtin_nontemporal_store(o, &outr[tid + i * BLOCK]);
    }
}

extern "C" void kernel_launch(void* const* d_in, const int* in_sizes, int n_in,
                              void* d_out, int out_size, void* d_ws, size_t ws_size,
                              hipStream_t stream) {
    const float* x = (const float*)d_in[0];
    float* out = (float*)d_out;
    const int rows = in_sizes[0] / NCOLS;  // 8192
    loo_mean_kernel<<<rows, BLOCK, 0, stream>>>(x, out);
}

// Round 4
// 174.348 us; speedup vs baseline: 1.0926x; 1.0926x over previous
//
#include <hip/hip_runtime.h>

// Leave-one-out mean along dim 1.
// x: [8192, 16384] f32, out[b,i] = (row_sum[b] - x[b,i]) / (NCOLS - 1).
// Round 4: back to 1024 threads (R3's 512 regressed). Two rows per block,
// software-pipelined: all loads for both rows issue up-front (128 KB in
// flight), both wave-reduces interleaved (ILP), ONE barrier for both rows,
// all-thread LDS partial sum (no serial tid==0 step), then both stores.
// Nontemporal loads+stores kept (touch-once streams).

#define NCOLS 16384
#define BLOCK 1024
#define PR 4   // float4 per thread per row = NCOLS/4/BLOCK
#define NWAVE (BLOCK / 64)

using f32x4 = __attribute__((ext_vector_type(4))) float;

__global__ __launch_bounds__(BLOCK, 8) void loo_mean_kernel(
    const float* __restrict__ x, float* __restrict__ out) {
    const size_t row0 = (size_t)blockIdx.x * 2;
    const f32x4* __restrict__ xr0 =
        reinterpret_cast<const f32x4*>(x + row0 * NCOLS);
    const f32x4* __restrict__ xr1 = xr0 + NCOLS / 4;
    f32x4* __restrict__ or0 = reinterpret_cast<f32x4*>(out + row0 * NCOLS);
    f32x4* __restrict__ or1 = or0 + NCOLS / 4;
    const int tid = threadIdx.x;

    f32x4 a[PR], b[PR];
#pragma unroll
    for (int i = 0; i < PR; ++i)
        a[i] = __builtin_nontemporal_load(&xr0[tid + i * BLOCK]);
#pragma unroll
    for (int i = 0; i < PR; ++i)
        b[i] = __builtin_nontemporal_load(&xr1[tid + i * BLOCK]);

    float sa = 0.0f, sb = 0.0f;
#pragma unroll
    for (int i = 0; i < PR; ++i) {
        sa += (a[i].x + a[i].y) + (a[i].z + a[i].w);
        sb += (b[i].x + b[i].y) + (b[i].z + b[i].w);
    }

    // Interleaved wave-64 reductions (two independent shfl chains)
#pragma unroll
    for (int off = 32; off >= 1; off >>= 1) {
        sa += __shfl_down(sa, off, 64);
        sb += __shfl_down(sb, off, 64);
    }

    __shared__ float pA[NWAVE], pB[NWAVE];
    const int wave = tid >> 6;
    const int lane = tid & 63;
    if (lane == 0) { pA[wave] = sa; pB[wave] = sb; }
    __syncthreads();

    float ta = 0.0f, tb = 0.0f;
#pragma unroll
    for (int w = 0; w < NWAVE; ++w) { ta += pA[w]; tb += pB[w]; }

    const float inv = 1.0f / (float)(NCOLS - 1);
#pragma unroll
    for (int i = 0; i < PR; ++i) {
        f32x4 o;
        o.x = (ta - a[i].x) * inv;
        o.y = (ta - a[i].y) * inv;
        o.z = (ta - a[i].z) * inv;
        o.w = (ta - a[i].w) * inv;
        __builtin_nontemporal_store(o, &or0[tid + i * BLOCK]);
    }
#pragma unroll
    for (int i = 0; i < PR; ++i) {
        f32x4 o;
        o.x = (tb - b[i].x) * inv;
        o.y = (tb - b[i].y) * inv;
        o.z = (tb - b[i].z) * inv;
        o.w = (tb - b[i].w) * inv;
        __builtin_nontemporal_store(o, &or1[tid + i * BLOCK]);
    }
}

extern "C" void kernel_launch(void* const* d_in, const int* in_sizes, int n_in,
                              void* d_out, int out_size, void* d_ws, size_t ws_size,
                              hipStream_t stream) {
    const float* x = (const float*)d_in[0];
    float* out = (float*)d_out;
    const int rows = in_sizes[0] / NCOLS;  // 8192
    loo_mean_kernel<<<rows / 2, BLOCK, 0, stream>>>(x, out);
}